// Round 2
// baseline (3825.479 us; speedup 1.0000x reference)
//
#include <hip/hip_runtime.h>
#include <hip/hip_bf16.h>
#include <math.h>

#define D_MODEL 1024
#define NUM_HEADS 16
#define D_K 64
#define SEQ 1024
#define BATCH 2

typedef __hip_bfloat16 bf16;

// ---------------------------------------------------------------------------
// Dtype probe: inputs may be fp32 (per reference) or bf16 (harness-converted).
// Read first 4096 words of x as fp32. True fp32 N(0,1): ~100% in sane range.
// bf16 buffer misread as fp32: exponent field comes from a bf16's mid-bits ->
// |v| ~ 2^100+ or NaN -> ~0% sane. Flag: 1 = fp32 inputs, 0 = bf16 inputs.
// ---------------------------------------------------------------------------
__global__ void detect_dtype_kernel(const void* __restrict__ x, int* __restrict__ flag) {
    __shared__ int cnt[256];
    const float* xf = (const float*)x;
    const int tid = threadIdx.x;
    int sane = 0;
    for (int i = tid; i < 4096; i += 256) {
        float v = xf[i];
        float a = fabsf(v);
        if (v == 0.0f || (a > 1e-8f && a < 1e8f)) sane++;  // NaN/Inf fail both
    }
    cnt[tid] = sane;
    __syncthreads();
    for (int s = 128; s > 0; s >>= 1) {
        if (tid < s) cnt[tid] += cnt[tid + s];
        __syncthreads();
    }
    if (tid == 0) flag[0] = (cnt[0] > 3686) ? 1 : 0;  // >90% sane -> fp32
}

// Canonicalize an input to bf16 regardless of source dtype.
__global__ void convert_kernel(const void* __restrict__ src, bf16* __restrict__ dst,
                               int n, const int* __restrict__ flag) {
    const int i = blockIdx.x * 256 + threadIdx.x;
    if (i >= n) return;
    if (*flag)
        dst[i] = (bf16)((const float*)src)[i];
    else
        dst[i] = ((const bf16*)src)[i];
}

// ---------------------------------------------------------------------------
// GEMM: C[m,n] = bias[n] + sum_k A[m,k] * W[n,k]   (fp32 accumulate)
// DUAL=true: store per runtime flag (fp32 vs bf16); else always bf16.
// ---------------------------------------------------------------------------
#define TILE 16
template <bool DUAL>
__global__ void gemm_bt_kernel(const bf16* __restrict__ A, const bf16* __restrict__ W,
                               const bf16* __restrict__ bias, void* __restrict__ C,
                               int M, int N, int K, const int* __restrict__ flag) {
    __shared__ float As[TILE][TILE + 1];
    __shared__ float Ws[TILE][TILE + 1];
    const int tx = threadIdx.x, ty = threadIdx.y;
    const int m = blockIdx.y * TILE + ty;
    const int n = blockIdx.x * TILE + tx;
    const int wrow = blockIdx.x * TILE + ty;
    float acc = 0.f;
    for (int k0 = 0; k0 < K; k0 += TILE) {
        As[ty][tx] = (float)A[(size_t)m * K + k0 + tx];
        Ws[ty][tx] = (float)W[(size_t)wrow * K + k0 + tx];
        __syncthreads();
#pragma unroll
        for (int kk = 0; kk < TILE; ++kk)
            acc += As[ty][kk] * Ws[tx][kk];
        __syncthreads();
    }
    const float r = acc + (float)bias[n];
    const size_t idx = (size_t)m * N + n;
    if (DUAL) {
        if (*flag) ((float*)C)[idx] = r;
        else       ((bf16*)C)[idx] = (bf16)r;
    } else {
        ((bf16*)C)[idx] = (bf16)r;
    }
}

// ---------------------------------------------------------------------------
// Attention: one block per (query i, head h, batch b). 256 threads.
// scores[j] = (1/8) * sum_d q_d * (K[j,d] + Er[S-1+i-j, d]); softmax; P.V.
// ---------------------------------------------------------------------------
__device__ __forceinline__ float block_reduce_max(float v, float* rbuf, int tid) {
    rbuf[tid] = v;
    __syncthreads();
    for (int s = 128; s > 0; s >>= 1) {
        if (tid < s) rbuf[tid] = fmaxf(rbuf[tid], rbuf[tid + s]);
        __syncthreads();
    }
    float r = rbuf[0];
    __syncthreads();
    return r;
}

__device__ __forceinline__ float block_reduce_sum(float v, float* rbuf, int tid) {
    rbuf[tid] = v;
    __syncthreads();
    for (int s = 128; s > 0; s >>= 1) {
        if (tid < s) rbuf[tid] += rbuf[tid + s];
        __syncthreads();
    }
    float r = rbuf[0];
    __syncthreads();
    return r;
}

__global__ __launch_bounds__(256) void attn_kernel(const bf16* __restrict__ Q,
                                                   const bf16* __restrict__ K,
                                                   const bf16* __restrict__ V,
                                                   const bf16* __restrict__ Er,
                                                   bf16* __restrict__ O) {
    const int i = blockIdx.x;
    const int h = blockIdx.y;
    const int b = blockIdx.z;
    const int tid = threadIdx.x;

    __shared__ float q[D_K];
    __shared__ float sc[SEQ];
    __shared__ float rbuf[256];
    __shared__ float red[4][D_K];

    const size_t row_i = (size_t)(b * SEQ + i);
    const bf16* Qrow = Q + row_i * D_MODEL + h * D_K;
    if (tid < D_K) q[tid] = (float)Qrow[tid];
    __syncthreads();

    const bf16* Kbase = K + (size_t)b * SEQ * D_MODEL + h * D_K;
    const float scale = 0.125f;  // 1/sqrt(64)

    for (int j = tid; j < SEQ; j += 256) {
        const bf16* Krow = Kbase + (size_t)j * D_MODEL;
        const bf16* Erow = Er + (size_t)(SEQ - 1 + i - j) * D_K;
        float s = 0.f;
#pragma unroll
        for (int d = 0; d < D_K; ++d)
            s += q[d] * ((float)Krow[d] + (float)Erow[d]);
        sc[j] = s * scale;
    }
    __syncthreads();

    float lmax = -INFINITY;
    for (int j = tid; j < SEQ; j += 256) lmax = fmaxf(lmax, sc[j]);
    const float gmax = block_reduce_max(lmax, rbuf, tid);

    float lsum = 0.f;
    for (int j = tid; j < SEQ; j += 256) {
        float e = __expf(sc[j] - gmax);
        sc[j] = e;
        lsum += e;
    }
    const float gsum = block_reduce_sum(lsum, rbuf, tid);
    const float inv = 1.0f / gsum;
    for (int j = tid; j < SEQ; j += 256) sc[j] *= inv;
    __syncthreads();

    const int d = tid & 63;
    const int g = tid >> 6;
    const bf16* Vcol = V + (size_t)b * SEQ * D_MODEL + h * D_K + d;
    float acc = 0.f;
    for (int j = g; j < SEQ; j += 4)
        acc += sc[j] * (float)Vcol[(size_t)j * D_MODEL];
    red[g][d] = acc;
    __syncthreads();
    if (tid < D_K) {
        float o = red[0][tid] + red[1][tid] + red[2][tid] + red[3][tid];
        O[row_i * D_MODEL + h * D_K + tid] = (bf16)o;
    }
}

// ---------------------------------------------------------------------------
extern "C" void kernel_launch(void* const* d_in, const int* in_sizes, int n_in,
                              void* d_out, int out_size, void* d_ws, size_t ws_size,
                              hipStream_t stream) {
    const int M = BATCH * SEQ;                    // 2048
    const size_t E_X  = (size_t)M * D_MODEL;      // 2097152
    const size_t E_W  = (size_t)D_MODEL * D_MODEL;
    const size_t E_B  = D_MODEL;
    const size_t E_ER = (size_t)2048 * D_K;       // MAX_LEN * D_K = 131072

    // Workspace layout: [flag(16B)] then bf16 canonical inputs, then Q/K/V/O.
    char* ws = (char*)d_ws;
    int* flag = (int*)ws;
    bf16* p = (bf16*)(ws + 16);
    bf16* xc  = p;           p += E_X;
    bf16* Wqc = p;           p += E_W;
    bf16* Wkc = p;           p += E_W;
    bf16* Wvc = p;           p += E_W;
    bf16* Woc = p;           p += E_W;
    bf16* bqc = p;           p += E_B;
    bf16* bkc = p;           p += E_B;
    bf16* bvc = p;           p += E_B;
    bf16* boc = p;           p += E_B;
    bf16* Erc = p;           p += E_ER;
    bf16* Qb  = p;           p += E_X;
    bf16* Kb  = p;           p += E_X;
    bf16* Vb  = p;           p += E_X;
    bf16* Ob  = p;           p += E_X;

    detect_dtype_kernel<<<1, 256, 0, stream>>>(d_in[0], flag);

    const void* srcs[10] = {d_in[0], d_in[1], d_in[3], d_in[5], d_in[7],
                            d_in[2], d_in[4], d_in[6], d_in[8], d_in[9]};
    bf16* dsts[10] = {xc, Wqc, Wkc, Wvc, Woc, bqc, bkc, bvc, boc, Erc};
    const int lens[10] = {(int)E_X, (int)E_W, (int)E_W, (int)E_W, (int)E_W,
                          (int)E_B, (int)E_B, (int)E_B, (int)E_B, (int)E_ER};
    for (int t = 0; t < 10; ++t)
        convert_kernel<<<(lens[t] + 255) / 256, 256, 0, stream>>>(srcs[t], dsts[t], lens[t], flag);

    dim3 blk(TILE, TILE);
    dim3 grd(D_MODEL / TILE, M / TILE);

    gemm_bt_kernel<false><<<grd, blk, 0, stream>>>(xc, Wqc, bqc, Qb, M, D_MODEL, D_MODEL, flag);
    gemm_bt_kernel<false><<<grd, blk, 0, stream>>>(xc, Wkc, bkc, Kb, M, D_MODEL, D_MODEL, flag);
    gemm_bt_kernel<false><<<grd, blk, 0, stream>>>(xc, Wvc, bvc, Vb, M, D_MODEL, D_MODEL, flag);

    attn_kernel<<<dim3(SEQ, NUM_HEADS, BATCH), 256, 0, stream>>>(Qb, Kb, Vb, Erc, Ob);

    gemm_bt_kernel<true><<<grd, blk, 0, stream>>>(Ob, Woc, boc, d_out, M, D_MODEL, D_MODEL, flag);
}

// Round 3
// 226.965 us; speedup vs baseline: 16.8549x; 16.8549x over previous
//
#include <hip/hip_runtime.h>
#include <hip/hip_bf16.h>
#include <math.h>

#define D_MODEL 1024
#define NUM_HEADS 16
#define D_K 64
#define SEQ 1024
#define BATCH 2

typedef __hip_bfloat16 bf16;
typedef __bf16 bf16x8 __attribute__((ext_vector_type(8)));
typedef float floatx4 __attribute__((ext_vector_type(4)));

__device__ __forceinline__ floatx4 mfma16(bf16x8 a, bf16x8 b, floatx4 c) {
    return __builtin_amdgcn_mfma_f32_16x16x32_bf16(a, b, c, 0, 0, 0);
}

// ---------------------------------------------------------------------------
// Dtype probe (unchanged from round 2 — it worked): flag=1 -> fp32 inputs.
// ---------------------------------------------------------------------------
__global__ void detect_dtype_kernel(const void* __restrict__ x, int* __restrict__ flag) {
    __shared__ int cnt[256];
    const float* xf = (const float*)x;
    const int tid = threadIdx.x;
    int sane = 0;
    for (int i = tid; i < 4096; i += 256) {
        float v = xf[i];
        float a = fabsf(v);
        if (v == 0.0f || (a > 1e-8f && a < 1e8f)) sane++;
    }
    cnt[tid] = sane;
    __syncthreads();
    for (int s = 128; s > 0; s >>= 1) {
        if (tid < s) cnt[tid] += cnt[tid + s];
        __syncthreads();
    }
    if (tid == 0) flag[0] = (cnt[0] > 3686) ? 1 : 0;
}

// Canonicalize an input to bf16, 8 elements per thread.
__global__ void convert_kernel(const void* __restrict__ src, bf16* __restrict__ dst,
                               int n, const int* __restrict__ flag) {
    const int i = (blockIdx.x * 256 + threadIdx.x) * 8;
    if (i >= n) return;
    if (*flag) {
        const float* s = (const float*)src + i;
        __bf16 tmp[8];
#pragma unroll
        for (int t = 0; t < 8; ++t) tmp[t] = (__bf16)s[t];
        *(bf16x8*)(void*)(dst + i) = *(const bf16x8*)tmp;
    } else {
        *(bf16x8*)(void*)(dst + i) = *(const bf16x8*)(const void*)((const bf16*)src + i);
    }
}

// ---------------------------------------------------------------------------
// MFMA GEMM: C[m,n] = bias[n] + sum_k A[m,k] * W[n,k]   (fp32 accumulate)
// Block tile 64x64, BK=64, 256 threads (4 waves), wave -> 32x32 (2x2 MFMA frags).
// A and W are both K-major, so A- and B-operand fragments are contiguous 16B.
// ---------------------------------------------------------------------------
template <bool DUAL>
__global__ __launch_bounds__(256) void gemm_mfma_kernel(const bf16* __restrict__ A,
                                                        const bf16* __restrict__ W,
                                                        const bf16* __restrict__ bias,
                                                        void* __restrict__ C,
                                                        int M, int N, int K,
                                                        const int* __restrict__ flag) {
    __shared__ __bf16 As[64][72];   // +8 pad keeps rows 16B-aligned, breaks bank aliasing
    __shared__ __bf16 Bs[64][72];
    const int tid = threadIdx.x;
    const int wave = tid >> 6, lane = tid & 63;
    const int quad = lane >> 4, l16 = lane & 15;
    const int m0 = blockIdx.y * 64, n0 = blockIdx.x * 64;
    const int wr = (wave >> 1) * 32, wc = (wave & 1) * 32;

    floatx4 acc[2][2];
#pragma unroll
    for (int r = 0; r < 2; ++r)
#pragma unroll
        for (int c = 0; c < 2; ++c) acc[r][c] = (floatx4)0.f;

    const int srow = tid >> 2;        // 0..63
    const int scol = (tid & 3) * 16;  // 0,16,32,48

    for (int k0 = 0; k0 < K; k0 += 64) {
        const bf16* ag = A + (size_t)(m0 + srow) * K + k0 + scol;
        const bf16* bg = W + (size_t)(n0 + srow) * K + k0 + scol;
        bf16x8 a0 = *(const bf16x8*)(const void*)ag;
        bf16x8 a1 = *(const bf16x8*)(const void*)(ag + 8);
        bf16x8 b0 = *(const bf16x8*)(const void*)bg;
        bf16x8 b1 = *(const bf16x8*)(const void*)(bg + 8);
        *(bf16x8*)&As[srow][scol]     = a0;
        *(bf16x8*)&As[srow][scol + 8] = a1;
        *(bf16x8*)&Bs[srow][scol]     = b0;
        *(bf16x8*)&Bs[srow][scol + 8] = b1;
        __syncthreads();
#pragma unroll
        for (int kk = 0; kk < 2; ++kk) {
            bf16x8 af[2], bf[2];
#pragma unroll
            for (int r = 0; r < 2; ++r)
                af[r] = *(const bf16x8*)&As[wr + r * 16 + l16][kk * 32 + quad * 8];
#pragma unroll
            for (int c = 0; c < 2; ++c)
                bf[c] = *(const bf16x8*)&Bs[wc + c * 16 + l16][kk * 32 + quad * 8];
#pragma unroll
            for (int r = 0; r < 2; ++r)
#pragma unroll
                for (int c = 0; c < 2; ++c)
                    acc[r][c] = mfma16(af[r], bf[c], acc[r][c]);
        }
        __syncthreads();
    }

#pragma unroll
    for (int c = 0; c < 2; ++c) {
        const int col = n0 + wc + c * 16 + l16;
        const float bv = (float)bias[col];
#pragma unroll
        for (int r = 0; r < 2; ++r) {
#pragma unroll
            for (int v = 0; v < 4; ++v) {
                const int row = m0 + wr + r * 16 + quad * 4 + v;
                const float val = acc[r][c][v] + bv;
                const size_t idx = (size_t)row * N + col;
                if (DUAL) {
                    if (*flag) ((float*)C)[idx] = val;
                    else       ((bf16*)C)[idx] = (bf16)val;
                } else {
                    ((bf16*)C)[idx] = (bf16)val;
                }
            }
        }
    }
}

// ---------------------------------------------------------------------------
// Flash attention with relative positions, MFMA.
// Block: 64 q-rows x (head, batch). 4 waves; wave w owns q-rows [16w,16w+16).
// score[i,j] = ( Q[i].K[j] + Q[i].Er[S-1+i-j] ) / 8 ; online softmax; O = P.V
// BD tile per wave: T[r, c] = Q[i0+16w+r] . Er[er0 + 16w + c], c in [0,80);
// gathered as BD[r, j'] = T[r, 63 + r - j'].   er0 = S-1 + i0 - j0 - 63.
// ---------------------------------------------------------------------------
__global__ __launch_bounds__(256) void attn_mfma_kernel(const bf16* __restrict__ Q,
                                                        const bf16* __restrict__ K,
                                                        const bf16* __restrict__ V,
                                                        const bf16* __restrict__ Er,
                                                        bf16* __restrict__ O) {
    const int i0 = blockIdx.x * 64;
    const int h  = blockIdx.y;
    const int b  = blockIdx.z;
    const int tid = threadIdx.x;
    const int wave = tid >> 6, lane = tid & 63;
    const int quad = lane >> 4, l16 = lane & 15;

    __shared__ __bf16 Qs[64][72];
    __shared__ __bf16 Ks[64][72];
    __shared__ __bf16 Vts[64][72];     // V transposed: Vts[d][j]
    __shared__ __bf16 Ers[128][72];    // Er window rows
    __shared__ __bf16 scratch[4][1280];  // per-wave: T view [16][80] / P view [16][72]

    __bf16* Tw = &scratch[wave][0];   // stride 80
    __bf16* Pw = &scratch[wave][0];   // stride 72

    const size_t hbase = (size_t)b * SEQ * D_MODEL + h * 64;

    {   // stage Q tile once
        const int r = tid >> 2, cg = (tid & 3) * 16;
        const bf16* g = Q + hbase + (size_t)(i0 + r) * D_MODEL + cg;
        *(bf16x8*)&Qs[r][cg]     = *(const bf16x8*)(const void*)g;
        *(bf16x8*)&Qs[r][cg + 8] = *(const bf16x8*)(const void*)(g + 8);
    }

    floatx4 oacc[4];
#pragma unroll
    for (int c = 0; c < 4; ++c) oacc[c] = (floatx4)0.f;
    float mrow[4], lrow[4];
#pragma unroll
    for (int v = 0; v < 4; ++v) { mrow[v] = -1e30f; lrow[v] = 0.f; }

    const int er_base = 960 + i0;  // (S-1) + i0 - 63

    for (int j0 = 0; j0 < SEQ; j0 += 64) {
        __syncthreads();
        {   // stage K, V^T, Er window
            const int r = tid >> 2, cg = (tid & 3) * 16;
            const bf16* kg = K + hbase + (size_t)(j0 + r) * D_MODEL + cg;
            *(bf16x8*)&Ks[r][cg]     = *(const bf16x8*)(const void*)kg;
            *(bf16x8*)&Ks[r][cg + 8] = *(const bf16x8*)(const void*)(kg + 8);
            const bf16* vg = V + hbase + (size_t)(j0 + r) * D_MODEL + cg;
            bf16x8 v0 = *(const bf16x8*)(const void*)vg;
            bf16x8 v1 = *(const bf16x8*)(const void*)(vg + 8);
#pragma unroll
            for (int t = 0; t < 8; ++t) Vts[cg + t][r] = v0[t];
#pragma unroll
            for (int t = 0; t < 8; ++t) Vts[cg + 8 + t][r] = v1[t];
            const int tr = tid >> 1, ecg = (tid & 1) * 32;
            const bf16* eg = Er + (size_t)(er_base - j0 + tr) * 64 + ecg;
            *(bf16x8*)&Ers[tr][ecg]      = *(const bf16x8*)(const void*)eg;
            *(bf16x8*)&Ers[tr][ecg + 8]  = *(const bf16x8*)(const void*)(eg + 8);
            *(bf16x8*)&Ers[tr][ecg + 16] = *(const bf16x8*)(const void*)(eg + 16);
            *(bf16x8*)&Ers[tr][ecg + 24] = *(const bf16x8*)(const void*)(eg + 24);
        }
        __syncthreads();

        bf16x8 aq0 = *(const bf16x8*)&Qs[wave * 16 + l16][quad * 8];
        bf16x8 aq1 = *(const bf16x8*)&Qs[wave * 16 + l16][32 + quad * 8];

        // AC = Q . K^T  (4 col-tiles of 16)
        floatx4 sfrag[4];
#pragma unroll
        for (int ct = 0; ct < 4; ++ct) {
            floatx4 a = (floatx4)0.f;
            bf16x8 bk0 = *(const bf16x8*)&Ks[ct * 16 + l16][quad * 8];
            bf16x8 bk1 = *(const bf16x8*)&Ks[ct * 16 + l16][32 + quad * 8];
            a = mfma16(aq0, bk0, a);
            a = mfma16(aq1, bk1, a);
            sfrag[ct] = a;
        }
        // BD tile: T = Q . Er_window^T (5 col-tiles), spill to per-wave LDS
#pragma unroll
        for (int ct = 0; ct < 5; ++ct) {
            floatx4 a = (floatx4)0.f;
            bf16x8 be0 = *(const bf16x8*)&Ers[wave * 16 + ct * 16 + l16][quad * 8];
            bf16x8 be1 = *(const bf16x8*)&Ers[wave * 16 + ct * 16 + l16][32 + quad * 8];
            a = mfma16(aq0, be0, a);
            a = mfma16(aq1, be1, a);
#pragma unroll
            for (int v = 0; v < 4; ++v)
                Tw[(quad * 4 + v) * 80 + ct * 16 + l16] = (__bf16)a[v];
        }
        // gather BD, scale
#pragma unroll
        for (int ct = 0; ct < 4; ++ct) {
#pragma unroll
            for (int v = 0; v < 4; ++v) {
                const int r = quad * 4 + v;
                const int jj = ct * 16 + l16;
                sfrag[ct][v] = (sfrag[ct][v] + (float)Tw[r * 80 + 63 + r - jj]) * 0.125f;
            }
        }
        // online softmax (row = quad*4+v; reduce over 16 lanes of the quad)
        float alpha[4];
#pragma unroll
        for (int v = 0; v < 4; ++v) {
            float mx = fmaxf(fmaxf(sfrag[0][v], sfrag[1][v]), fmaxf(sfrag[2][v], sfrag[3][v]));
            for (int off = 1; off < 16; off <<= 1)
                mx = fmaxf(mx, __shfl_xor(mx, off, 64));
            const float mnew = fmaxf(mrow[v], mx);
            alpha[v] = __expf(mrow[v] - mnew);
            mrow[v] = mnew;
        }
        float rsum[4] = {0.f, 0.f, 0.f, 0.f};
#pragma unroll
        for (int ct = 0; ct < 4; ++ct) {
#pragma unroll
            for (int v = 0; v < 4; ++v) {
                const float p = __expf(sfrag[ct][v] - mrow[v]);
                sfrag[ct][v] = p;
                rsum[v] += p;
            }
        }
#pragma unroll
        for (int v = 0; v < 4; ++v) {
            float s = rsum[v];
            for (int off = 1; off < 16; off <<= 1)
                s += __shfl_xor(s, off, 64);
            lrow[v] = lrow[v] * alpha[v] + s;
        }
        // write P (bf16) to per-wave LDS in row-major [16][72]
#pragma unroll
        for (int ct = 0; ct < 4; ++ct)
#pragma unroll
            for (int v = 0; v < 4; ++v)
                Pw[(quad * 4 + v) * 72 + ct * 16 + l16] = (__bf16)sfrag[ct][v];
        // rescale O
#pragma unroll
        for (int c = 0; c < 4; ++c)
#pragma unroll
            for (int v = 0; v < 4; ++v)
                oacc[c][v] *= alpha[v];
        // O += P . V   (A = P in A-layout, B = V^T)
        bf16x8 ap0 = *(const bf16x8*)&Pw[l16 * 72 + quad * 8];
        bf16x8 ap1 = *(const bf16x8*)&Pw[l16 * 72 + 32 + quad * 8];
#pragma unroll
        for (int ct = 0; ct < 4; ++ct) {
            bf16x8 bv0 = *(const bf16x8*)&Vts[ct * 16 + l16][quad * 8];
            bf16x8 bv1 = *(const bf16x8*)&Vts[ct * 16 + l16][32 + quad * 8];
            oacc[ct] = mfma16(ap0, bv0, oacc[ct]);
            oacc[ct] = mfma16(ap1, bv1, oacc[ct]);
        }
    }

    // epilogue: O / l
#pragma unroll
    for (int ct = 0; ct < 4; ++ct) {
#pragma unroll
        for (int v = 0; v < 4; ++v) {
            const int row = i0 + wave * 16 + quad * 4 + v;
            const int col = h * 64 + ct * 16 + l16;
            const float o = oacc[ct][v] / lrow[v];
            O[((size_t)b * SEQ + row) * D_MODEL + col] = (bf16)o;
        }
    }
}

// ---------------------------------------------------------------------------
extern "C" void kernel_launch(void* const* d_in, const int* in_sizes, int n_in,
                              void* d_out, int out_size, void* d_ws, size_t ws_size,
                              hipStream_t stream) {
    const int M = BATCH * SEQ;                    // 2048
    const size_t E_X  = (size_t)M * D_MODEL;
    const size_t E_W  = (size_t)D_MODEL * D_MODEL;
    const size_t E_B  = D_MODEL;
    const size_t E_ER = (size_t)2048 * D_K;

    char* ws = (char*)d_ws;
    int* flag = (int*)ws;
    bf16* p = (bf16*)(ws + 16);
    bf16* xc  = p;  p += E_X;
    bf16* Wqc = p;  p += E_W;
    bf16* Wkc = p;  p += E_W;
    bf16* Wvc = p;  p += E_W;
    bf16* Woc = p;  p += E_W;
    bf16* bqc = p;  p += E_B;
    bf16* bkc = p;  p += E_B;
    bf16* bvc = p;  p += E_B;
    bf16* boc = p;  p += E_B;
    bf16* Erc = p;  p += E_ER;
    bf16* Qb  = p;  p += E_X;
    bf16* Kb  = p;  p += E_X;
    bf16* Vb  = p;  p += E_X;
    bf16* Ob  = p;  p += E_X;

    detect_dtype_kernel<<<1, 256, 0, stream>>>(d_in[0], flag);

    const void* srcs[10] = {d_in[0], d_in[1], d_in[3], d_in[5], d_in[7],
                            d_in[2], d_in[4], d_in[6], d_in[8], d_in[9]};
    bf16* dsts[10] = {xc, Wqc, Wkc, Wvc, Woc, bqc, bkc, bvc, boc, Erc};
    const int lens[10] = {(int)E_X, (int)E_W, (int)E_W, (int)E_W, (int)E_W,
                          (int)E_B, (int)E_B, (int)E_B, (int)E_B, (int)E_ER};
    for (int t = 0; t < 10; ++t) {
        const int nthr = (lens[t] + 7) / 8;
        convert_kernel<<<(nthr + 255) / 256, 256, 0, stream>>>(srcs[t], dsts[t], lens[t], flag);
    }

    dim3 blk(256);
    dim3 gg(D_MODEL / 64, M / 64);  // (16, 32)

    gemm_mfma_kernel<false><<<gg, blk, 0, stream>>>(xc, Wqc, bqc, Qb, M, D_MODEL, D_MODEL, flag);
    gemm_mfma_kernel<false><<<gg, blk, 0, stream>>>(xc, Wkc, bkc, Kb, M, D_MODEL, D_MODEL, flag);
    gemm_mfma_kernel<false><<<gg, blk, 0, stream>>>(xc, Wvc, bvc, Vb, M, D_MODEL, D_MODEL, flag);

    attn_mfma_kernel<<<dim3(SEQ / 64, NUM_HEADS, BATCH), blk, 0, stream>>>(Qb, Kb, Vb, Erc, Ob);

    gemm_mfma_kernel<true><<<gg, blk, 0, stream>>>(Ob, Woc, boc, d_out, M, D_MODEL, D_MODEL, flag);
}

// Round 4
// 204.300 us; speedup vs baseline: 18.7248x; 1.1109x over previous
//
#include <hip/hip_runtime.h>
#include <hip/hip_bf16.h>
#include <math.h>

#define D_MODEL 1024
#define NUM_HEADS 16
#define D_K 64
#define SEQ 1024
#define BATCH 2

typedef __hip_bfloat16 bf16;
typedef __bf16 bf16x8 __attribute__((ext_vector_type(8)));
typedef __bf16 bf16x4 __attribute__((ext_vector_type(4)));
typedef float floatx4 __attribute__((ext_vector_type(4)));

__device__ __forceinline__ floatx4 mfma16(bf16x8 a, bf16x8 b, floatx4 c) {
    return __builtin_amdgcn_mfma_f32_16x16x32_bf16(a, b, c, 0, 0, 0);
}

// ---------------------------------------------------------------------------
// Dtype probe: flag=1 -> fp32 inputs, 0 -> bf16 (verified working in r2/r3).
// ---------------------------------------------------------------------------
__global__ void detect_dtype_kernel(const void* __restrict__ x, int* __restrict__ flag) {
    __shared__ int cnt[256];
    const float* xf = (const float*)x;
    const int tid = threadIdx.x;
    int sane = 0;
    for (int i = tid; i < 4096; i += 256) {
        float v = xf[i];
        float a = fabsf(v);
        if (v == 0.0f || (a > 1e-8f && a < 1e8f)) sane++;
    }
    cnt[tid] = sane;
    __syncthreads();
    for (int s = 128; s > 0; s >>= 1) {
        if (tid < s) cnt[tid] += cnt[tid + s];
        __syncthreads();
    }
    if (tid == 0) flag[0] = (cnt[0] > 3686) ? 1 : 0;
}

// ---------------------------------------------------------------------------
// One fused convert: all 10 inputs -> contiguous canonical bf16 region.
// Segment order matches the workspace layout. All sizes are multiples of 8.
// ---------------------------------------------------------------------------
struct ConvSrcs { const void* p[10]; };

__global__ __launch_bounds__(256) void convert_all_kernel(ConvSrcs srcs,
                                                          bf16* __restrict__ dstbase,
                                                          const int* __restrict__ flag) {
    const long long e = ((long long)blockIdx.x * 256 + threadIdx.x) * 8;
    int seg; long long base;
    if      (e < 2097152LL) { seg = 0; base = 0; }          // x
    else if (e < 3145728LL) { seg = 1; base = 2097152LL; }  // Wq
    else if (e < 4194304LL) { seg = 2; base = 3145728LL; }  // Wk
    else if (e < 5242880LL) { seg = 3; base = 4194304LL; }  // Wv
    else if (e < 6291456LL) { seg = 4; base = 5242880LL; }  // Wo
    else if (e < 6292480LL) { seg = 5; base = 6291456LL; }  // bq
    else if (e < 6293504LL) { seg = 6; base = 6292480LL; }  // bk
    else if (e < 6294528LL) { seg = 7; base = 6293504LL; }  // bv
    else if (e < 6295552LL) { seg = 8; base = 6294528LL; }  // bo
    else                    { seg = 9; base = 6295552LL; }  // Er
    const long long local = e - base;
    __bf16 tmp[8];
    if (*flag) {
        const float* s = (const float*)srcs.p[seg] + local;
#pragma unroll
        for (int t = 0; t < 8; ++t) tmp[t] = (__bf16)s[t];
        *(bf16x8*)(void*)(dstbase + e) = *(const bf16x8*)tmp;
    } else {
        *(bf16x8*)(void*)(dstbase + e) =
            *(const bf16x8*)(const void*)((const bf16*)srcs.p[seg] + local);
    }
}

// ---------------------------------------------------------------------------
// Fused QKV GEMM: for wsel in {0,1,2}: C[m,n] = b[n] + sum_k x[m,k]*W[n,k]
// 128x128 block tile, BK=64, 4 waves each 64x64 (4x4 16x16x32 frags).
// ---------------------------------------------------------------------------
__global__ __launch_bounds__(256) void gemm_qkv_kernel(const bf16* __restrict__ x,
        const bf16* __restrict__ Wq, const bf16* __restrict__ Wk, const bf16* __restrict__ Wv,
        const bf16* __restrict__ bq, const bf16* __restrict__ bk, const bf16* __restrict__ bv,
        bf16* __restrict__ Qb, bf16* __restrict__ Kb, bf16* __restrict__ Vb) {
    const int wsel = blockIdx.x >> 3;
    const int n0 = (blockIdx.x & 7) * 128;
    const int m0 = blockIdx.y * 128;
    const bf16* W    = (wsel == 0) ? Wq : ((wsel == 1) ? Wk : Wv);
    const bf16* bias = (wsel == 0) ? bq : ((wsel == 1) ? bk : bv);
    bf16* Cb         = (wsel == 0) ? Qb : ((wsel == 1) ? Kb : Vb);

    __shared__ __bf16 As[128][72];
    __shared__ __bf16 Bs[128][72];
    const int tid = threadIdx.x;
    const int wave = tid >> 6, lane = tid & 63, quad = lane >> 4, l16 = lane & 15;
    const int wr = (wave >> 1) * 64, wc = (wave & 1) * 64;
    const int srow = tid >> 1, scg = (tid & 1) * 32;

    floatx4 acc[4][4];
#pragma unroll
    for (int r = 0; r < 4; ++r)
#pragma unroll
        for (int c = 0; c < 4; ++c) acc[r][c] = (floatx4)0.f;

    for (int k0 = 0; k0 < 1024; k0 += 64) {
        const bf16* ag = x + (size_t)(m0 + srow) * 1024 + k0 + scg;
        const bf16* bg = W + (size_t)(n0 + srow) * 1024 + k0 + scg;
        bf16x8 av[4], bv[4];
#pragma unroll
        for (int c = 0; c < 4; ++c) {
            av[c] = *(const bf16x8*)(const void*)(ag + c * 8);
            bv[c] = *(const bf16x8*)(const void*)(bg + c * 8);
        }
        __syncthreads();
#pragma unroll
        for (int c = 0; c < 4; ++c) {
            *(bf16x8*)&As[srow][scg + c * 8] = av[c];
            *(bf16x8*)&Bs[srow][scg + c * 8] = bv[c];
        }
        __syncthreads();
#pragma unroll
        for (int kk = 0; kk < 2; ++kk) {
            bf16x8 af[4], bfr[4];
#pragma unroll
            for (int r = 0; r < 4; ++r)
                af[r] = *(const bf16x8*)&As[wr + r * 16 + l16][kk * 32 + quad * 8];
#pragma unroll
            for (int c = 0; c < 4; ++c)
                bfr[c] = *(const bf16x8*)&Bs[wc + c * 16 + l16][kk * 32 + quad * 8];
#pragma unroll
            for (int r = 0; r < 4; ++r)
#pragma unroll
                for (int c = 0; c < 4; ++c)
                    acc[r][c] = mfma16(af[r], bfr[c], acc[r][c]);
        }
    }
#pragma unroll
    for (int c = 0; c < 4; ++c) {
        const int col = n0 + wc + c * 16 + l16;
        const float bvl = (float)bias[col];
#pragma unroll
        for (int r = 0; r < 4; ++r)
#pragma unroll
            for (int v = 0; v < 4; ++v) {
                const int row = m0 + wr + r * 16 + quad * 4 + v;
                Cb[(size_t)row * 1024 + col] = (bf16)(acc[r][c][v] + bvl);
            }
    }
}

// ---------------------------------------------------------------------------
// Output GEMM: out[m,n] = bo[n] + sum_k Ob[m,k]*Wo[n,k]. 128x64 tile, dual store.
// ---------------------------------------------------------------------------
__global__ __launch_bounds__(256) void gemm_out_kernel(const bf16* __restrict__ A,
        const bf16* __restrict__ W, const bf16* __restrict__ bias,
        void* __restrict__ C, const int* __restrict__ flag) {
    const int n0 = blockIdx.x * 64;
    const int m0 = blockIdx.y * 128;
    __shared__ __bf16 As[128][72];
    __shared__ __bf16 Bs[64][72];
    const int tid = threadIdx.x;
    const int wave = tid >> 6, lane = tid & 63, quad = lane >> 4, l16 = lane & 15;
    const int wr = (wave >> 1) * 64, wc = (wave & 1) * 32;
    const int arow = tid >> 1, acg = (tid & 1) * 32;
    const int brow = tid >> 2, bcg = (tid & 3) * 16;

    floatx4 acc[4][2];
#pragma unroll
    for (int r = 0; r < 4; ++r)
#pragma unroll
        for (int c = 0; c < 2; ++c) acc[r][c] = (floatx4)0.f;

    for (int k0 = 0; k0 < 1024; k0 += 64) {
        const bf16* ag = A + (size_t)(m0 + arow) * 1024 + k0 + acg;
        const bf16* bg = W + (size_t)(n0 + brow) * 1024 + k0 + bcg;
        bf16x8 av[4], bv[2];
#pragma unroll
        for (int c = 0; c < 4; ++c) av[c] = *(const bf16x8*)(const void*)(ag + c * 8);
#pragma unroll
        for (int c = 0; c < 2; ++c) bv[c] = *(const bf16x8*)(const void*)(bg + c * 8);
        __syncthreads();
#pragma unroll
        for (int c = 0; c < 4; ++c) *(bf16x8*)&As[arow][acg + c * 8] = av[c];
#pragma unroll
        for (int c = 0; c < 2; ++c) *(bf16x8*)&Bs[brow][bcg + c * 8] = bv[c];
        __syncthreads();
#pragma unroll
        for (int kk = 0; kk < 2; ++kk) {
            bf16x8 af[4], bfr[2];
#pragma unroll
            for (int r = 0; r < 4; ++r)
                af[r] = *(const bf16x8*)&As[wr + r * 16 + l16][kk * 32 + quad * 8];
#pragma unroll
            for (int c = 0; c < 2; ++c)
                bfr[c] = *(const bf16x8*)&Bs[wc + c * 16 + l16][kk * 32 + quad * 8];
#pragma unroll
            for (int r = 0; r < 4; ++r)
#pragma unroll
                for (int c = 0; c < 2; ++c)
                    acc[r][c] = mfma16(af[r], bfr[c], acc[r][c]);
        }
    }
#pragma unroll
    for (int c = 0; c < 2; ++c) {
        const int col = n0 + wc + c * 16 + l16;
        const float bvl = (float)bias[col];
#pragma unroll
        for (int r = 0; r < 4; ++r)
#pragma unroll
            for (int v = 0; v < 4; ++v) {
                const int row = m0 + wr + r * 16 + quad * 4 + v;
                const float val = acc[r][c][v] + bvl;
                const size_t idx = (size_t)row * 1024 + col;
                if (*flag) ((float*)C)[idx] = val;
                else       ((bf16*)C)[idx] = (bf16)val;
            }
    }
}

// ---------------------------------------------------------------------------
// V pre-transpose: Vt[(b*16+h)*64 + d][s] = V[b*1024+s][h*64+d]. LDS-tiled.
// ---------------------------------------------------------------------------
__global__ __launch_bounds__(256) void transpose_v_kernel(const bf16* __restrict__ V,
                                                          bf16* __restrict__ Vt) {
    __shared__ __bf16 Ls[64][72];
    const int s0 = blockIdx.x * 64;
    const int h = blockIdx.y, b = blockIdx.z;
    const int tid = threadIdx.x;
    {
        const int r = tid >> 2, cg = (tid & 3) * 16;
        const bf16* g = V + ((size_t)(b * SEQ + s0 + r)) * D_MODEL + h * 64 + cg;
        *(bf16x8*)&Ls[r][cg]     = *(const bf16x8*)(const void*)g;
        *(bf16x8*)&Ls[r][cg + 8] = *(const bf16x8*)(const void*)(g + 8);
    }
    __syncthreads();
    {
        const int d = tid >> 2, cs = (tid & 3) * 16;
        __bf16 tmp[16];
#pragma unroll
        for (int t = 0; t < 16; ++t) tmp[t] = Ls[cs + t][d];
        bf16* g = Vt + ((size_t)((b * NUM_HEADS + h) * 64 + d)) * SEQ + s0 + cs;
        *(bf16x8*)(void*)g       = *(const bf16x8*)tmp;
        *(bf16x8*)(void*)(g + 8) = *(const bf16x8*)(tmp + 8);
    }
}

// ---------------------------------------------------------------------------
// Flash attention with relative positions. Block = 64 q-rows x (h,b), 128 thr,
// 2 waves x 32 rows. j-tile 64. BD via per-wave T tile spilled TRANSPOSED
// (b64 vector writes) into scratch overlaid on the Ers region (barrier #2
// separates all Ers b-frag reads from scratch writes).
//   score(i,j) = ( Q[i].K[j] + Q[i].Er[S-1+i-j] ) / 8
//   wave-local: T[rl][cl] = Q[i0+32w+rl] . Er[eb-j0 + 32w + cl], cl in [0,96)
//   BD[rl][wj] = T[rl][63 + rl - wj],   eb = 960 + i0.
// ---------------------------------------------------------------------------
__global__ __launch_bounds__(128) void attn_mfma_kernel(const bf16* __restrict__ Q,
                                                        const bf16* __restrict__ Kc,
                                                        const bf16* __restrict__ Vt,
                                                        const bf16* __restrict__ Er,
                                                        bf16* __restrict__ O) {
    const int i0 = blockIdx.x * 64;
    const int h = blockIdx.y, b = blockIdx.z;
    const int tid = threadIdx.x;
    const int wave = tid >> 6, lane = tid & 63, quad = lane >> 4, l16 = lane & 15;

    __shared__ __bf16 Qs[64][72];
    __shared__ __bf16 Ks[64][72];
    __shared__ __bf16 Vs[64][72];    // Vs[d][j_local]
    __shared__ __bf16 Ers[128][72];  // Er window; also scratch overlay (T'/P)
    __bf16* scr = &Ers[0][0] + wave * 3456;  // per-wave 6912 B

    const size_t qk_base = (size_t)b * SEQ * D_MODEL + h * 64;

    {   // stage Q once
        const int r = tid >> 1, cg = (tid & 1) * 32;
        const bf16* g = Q + qk_base + (size_t)(i0 + r) * D_MODEL + cg;
#pragma unroll
        for (int c = 0; c < 32; c += 8)
            *(bf16x8*)&Qs[r][cg + c] = *(const bf16x8*)(const void*)(g + c);
    }
    __syncthreads();
    bf16x8 aq[2][2];
#pragma unroll
    for (int half = 0; half < 2; ++half)
#pragma unroll
        for (int kk = 0; kk < 2; ++kk)
            aq[half][kk] = *(const bf16x8*)&Qs[wave * 32 + half * 16 + l16][kk * 32 + quad * 8];

    floatx4 oacc[4][2];
#pragma unroll
    for (int ct = 0; ct < 4; ++ct)
#pragma unroll
        for (int half = 0; half < 2; ++half) oacc[ct][half] = (floatx4)0.f;
    float m_i[2][4], l_i[2][4];
#pragma unroll
    for (int half = 0; half < 2; ++half)
#pragma unroll
        for (int v = 0; v < 4; ++v) { m_i[half][v] = -1e30f; l_i[half][v] = 0.f; }

    const int eb = 960 + i0;
    const bf16* Kg = Kc + qk_base;
    const bf16* Vtg = Vt + (size_t)((b * NUM_HEADS + h) * 64) * SEQ;

    for (int j0 = 0; j0 < SEQ; j0 += 64) {
        __syncthreads();  // barrier #1: prior-iter LDS reads (incl. scratch) done
        {   // stage K tile, V^T tile, Er window
            const int r = tid >> 1, cg = (tid & 1) * 32;
            const bf16* kg = Kg + (size_t)(j0 + r) * D_MODEL + cg;
            const bf16* vg = Vtg + (size_t)r * SEQ + j0 + cg;
#pragma unroll
            for (int c = 0; c < 32; c += 8) {
                *(bf16x8*)&Ks[r][cg + c] = *(const bf16x8*)(const void*)(kg + c);
                *(bf16x8*)&Vs[r][cg + c] = *(const bf16x8*)(const void*)(vg + c);
            }
            const bf16* eg = Er + (size_t)(eb - j0 + tid) * 64;
#pragma unroll
            for (int c = 0; c < 64; c += 8)
                *(bf16x8*)&Ers[tid][c] = *(const bf16x8*)(const void*)(eg + c);
        }
        __syncthreads();

        // AC = Q.K^T
        floatx4 sfrag[4][2];
#pragma unroll
        for (int ct = 0; ct < 4; ++ct) {
            bf16x8 bk0 = *(const bf16x8*)&Ks[ct * 16 + l16][quad * 8];
            bf16x8 bk1 = *(const bf16x8*)&Ks[ct * 16 + l16][32 + quad * 8];
#pragma unroll
            for (int half = 0; half < 2; ++half) {
                floatx4 s = (floatx4)0.f;
                s = mfma16(aq[half][0], bk0, s);
                s = mfma16(aq[half][1], bk1, s);
                sfrag[ct][half] = s;
            }
        }
        // BD tile into registers
        floatx4 tacc[6][2];
#pragma unroll
        for (int ct = 0; ct < 6; ++ct) {
            bf16x8 be0 = *(const bf16x8*)&Ers[wave * 32 + ct * 16 + l16][quad * 8];
            bf16x8 be1 = *(const bf16x8*)&Ers[wave * 32 + ct * 16 + l16][32 + quad * 8];
#pragma unroll
            for (int half = 0; half < 2; ++half) {
                floatx4 t = (floatx4)0.f;
                t = mfma16(aq[half][0], be0, t);
                t = mfma16(aq[half][1], be1, t);
                tacc[ct][half] = t;
            }
        }
        __syncthreads();  // barrier #2: all Ers reads done before scratch writes

        // spill T transposed: T'[cl][rl], rl consecutive -> b64 writes
#pragma unroll
        for (int ct = 0; ct < 6; ++ct)
#pragma unroll
            for (int half = 0; half < 2; ++half) {
                bf16x4 tv;
#pragma unroll
                for (int v = 0; v < 4; ++v) tv[v] = (__bf16)tacc[ct][half][v];
                *(bf16x4*)(void*)(scr + (ct * 16 + l16) * 36 + half * 16 + quad * 4) = tv;
            }
        // gather BD + scale
#pragma unroll
        for (int ct = 0; ct < 4; ++ct)
#pragma unroll
            for (int half = 0; half < 2; ++half)
#pragma unroll
                for (int v = 0; v < 4; ++v) {
                    const int rl = half * 16 + quad * 4 + v;
                    const int cl = 63 + rl - (ct * 16 + l16);
                    sfrag[ct][half][v] =
                        (sfrag[ct][half][v] + (float)scr[cl * 36 + rl]) * 0.125f;
                }
        // online softmax
        float alpha[2][4];
#pragma unroll
        for (int half = 0; half < 2; ++half) {
#pragma unroll
            for (int v = 0; v < 4; ++v) {
                float mx = fmaxf(fmaxf(sfrag[0][half][v], sfrag[1][half][v]),
                                 fmaxf(sfrag[2][half][v], sfrag[3][half][v]));
#pragma unroll
                for (int off = 1; off < 16; off <<= 1)
                    mx = fmaxf(mx, __shfl_xor(mx, off, 64));
                const float mnew = fmaxf(m_i[half][v], mx);
                alpha[half][v] = __expf(m_i[half][v] - mnew);
                m_i[half][v] = mnew;
            }
            float rs[4] = {0.f, 0.f, 0.f, 0.f};
#pragma unroll
            for (int ct = 0; ct < 4; ++ct)
#pragma unroll
                for (int v = 0; v < 4; ++v) {
                    const float p = __expf(sfrag[ct][half][v] - m_i[half][v]);
                    sfrag[ct][half][v] = p;
                    rs[v] += p;
                }
#pragma unroll
            for (int v = 0; v < 4; ++v) {
                float s = rs[v];
#pragma unroll
                for (int off = 1; off < 16; off <<= 1)
                    s += __shfl_xor(s, off, 64);
                l_i[half][v] = l_i[half][v] * alpha[half][v] + s;
            }
        }
        // write P (row-major, stride 72) into same scratch (T' dead)
#pragma unroll
        for (int ct = 0; ct < 4; ++ct)
#pragma unroll
            for (int half = 0; half < 2; ++half)
#pragma unroll
                for (int v = 0; v < 4; ++v)
                    scr[(half * 16 + quad * 4 + v) * 72 + ct * 16 + l16] =
                        (__bf16)sfrag[ct][half][v];
        // rescale O
#pragma unroll
        for (int ct = 0; ct < 4; ++ct)
#pragma unroll
            for (int half = 0; half < 2; ++half)
#pragma unroll
                for (int v = 0; v < 4; ++v) oacc[ct][half][v] *= alpha[half][v];
        // O += P.V
        bf16x8 ap[2][2];
#pragma unroll
        for (int half = 0; half < 2; ++half)
#pragma unroll
            for (int kk = 0; kk < 2; ++kk)
                ap[half][kk] =
                    *(const bf16x8*)(const void*)(scr + (half * 16 + l16) * 72 + kk * 32 + quad * 8);
#pragma unroll
        for (int ct = 0; ct < 4; ++ct) {
            bf16x8 bv0 = *(const bf16x8*)&Vs[ct * 16 + l16][quad * 8];
            bf16x8 bv1 = *(const bf16x8*)&Vs[ct * 16 + l16][32 + quad * 8];
#pragma unroll
            for (int half = 0; half < 2; ++half) {
                oacc[ct][half] = mfma16(ap[half][0], bv0, oacc[ct][half]);
                oacc[ct][half] = mfma16(ap[half][1], bv1, oacc[ct][half]);
            }
        }
    }
    // epilogue
#pragma unroll
    for (int ct = 0; ct < 4; ++ct)
#pragma unroll
        for (int half = 0; half < 2; ++half)
#pragma unroll
            for (int v = 0; v < 4; ++v) {
                const int row = i0 + wave * 32 + half * 16 + quad * 4 + v;
                const int col = h * 64 + ct * 16 + l16;
                O[((size_t)b * SEQ + row) * D_MODEL + col] =
                    (bf16)(oacc[ct][half][v] / l_i[half][v]);
            }
}

// ---------------------------------------------------------------------------
extern "C" void kernel_launch(void* const* d_in, const int* in_sizes, int n_in,
                              void* d_out, int out_size, void* d_ws, size_t ws_size,
                              hipStream_t stream) {
    const int M = BATCH * SEQ;                 // 2048
    const size_t E_X = (size_t)M * D_MODEL;    // 2097152
    const size_t E_CANON = 6426624;            // all canonical bf16 elems

    char* ws = (char*)d_ws;
    int* flag = (int*)ws;
    bf16* canon = (bf16*)(ws + 16);
    bf16* xc  = canon;
    bf16* Wqc = canon + 2097152;
    bf16* Wkc = canon + 3145728;
    bf16* Wvc = canon + 4194304;
    bf16* Woc = canon + 5242880;
    bf16* bqc = canon + 6291456;
    bf16* bkc = canon + 6292480;
    bf16* bvc = canon + 6293504;
    bf16* boc = canon + 6294528;
    bf16* Erc = canon + 6295552;
    bf16* p = canon + E_CANON;
    bf16* Qb = p;  p += E_X;
    bf16* Kb = p;  p += E_X;
    bf16* Vb = p;  p += E_X;
    bf16* Vt = p;  p += E_X;
    bf16* Ob = p;  p += E_X;

    detect_dtype_kernel<<<1, 256, 0, stream>>>(d_in[0], flag);

    ConvSrcs cs;
    cs.p[0] = d_in[0]; cs.p[1] = d_in[1]; cs.p[2] = d_in[3]; cs.p[3] = d_in[5];
    cs.p[4] = d_in[7]; cs.p[5] = d_in[2]; cs.p[6] = d_in[4]; cs.p[7] = d_in[6];
    cs.p[8] = d_in[8]; cs.p[9] = d_in[9];
    convert_all_kernel<<<3138, 256, 0, stream>>>(cs, canon, flag);

    gemm_qkv_kernel<<<dim3(24, 16), 256, 0, stream>>>(xc, Wqc, Wkc, Wvc,
                                                      bqc, bkc, bvc, Qb, Kb, Vb);

    transpose_v_kernel<<<dim3(16, NUM_HEADS, BATCH), 256, 0, stream>>>(Vb, Vt);

    attn_mfma_kernel<<<dim3(SEQ / 64, NUM_HEADS, BATCH), 128, 0, stream>>>(Qb, Kb, Vt, Erc, Ob);

    gemm_out_kernel<<<dim3(16, 16), 256, 0, stream>>>(Ob, Woc, boc, d_out, flag);
}

// Round 5
// 195.489 us; speedup vs baseline: 19.5687x; 1.0451x over previous
//
#include <hip/hip_runtime.h>
#include <hip/hip_bf16.h>
#include <math.h>

#define D_MODEL 1024
#define NUM_HEADS 16
#define D_K 64
#define SEQ 1024
#define BATCH 2

typedef __hip_bfloat16 bf16;
typedef __bf16 bf16x8 __attribute__((ext_vector_type(8)));
typedef __bf16 bf16x4 __attribute__((ext_vector_type(4)));
typedef float floatx4 __attribute__((ext_vector_type(4)));

__device__ __forceinline__ floatx4 mfma16(bf16x8 a, bf16x8 b, floatx4 c) {
    return __builtin_amdgcn_mfma_f32_16x16x32_bf16(a, b, c, 0, 0, 0);
}

// ---------------------------------------------------------------------------
// Dtype probe: flag=1 -> fp32 inputs, 0 -> bf16 (verified in r2-r4).
// ---------------------------------------------------------------------------
__global__ void detect_dtype_kernel(const void* __restrict__ x, int* __restrict__ flag) {
    __shared__ int cnt[256];
    const float* xf = (const float*)x;
    const int tid = threadIdx.x;
    int sane = 0;
    for (int i = tid; i < 4096; i += 256) {
        float v = xf[i];
        float a = fabsf(v);
        if (v == 0.0f || (a > 1e-8f && a < 1e8f)) sane++;
    }
    cnt[tid] = sane;
    __syncthreads();
    for (int s = 128; s > 0; s >>= 1) {
        if (tid < s) cnt[tid] += cnt[tid + s];
        __syncthreads();
    }
    if (tid == 0) flag[0] = (cnt[0] > 3686) ? 1 : 0;
}

// ---------------------------------------------------------------------------
// Fused convert of all 10 inputs into the canonical bf16 region.
// ---------------------------------------------------------------------------
struct ConvSrcs { const void* p[10]; };

__global__ __launch_bounds__(256) void convert_all_kernel(ConvSrcs srcs,
                                                          bf16* __restrict__ dstbase,
                                                          const int* __restrict__ flag) {
    const long long e = ((long long)blockIdx.x * 256 + threadIdx.x) * 8;
    int seg; long long base;
    if      (e < 2097152LL) { seg = 0; base = 0; }
    else if (e < 3145728LL) { seg = 1; base = 2097152LL; }
    else if (e < 4194304LL) { seg = 2; base = 3145728LL; }
    else if (e < 5242880LL) { seg = 3; base = 4194304LL; }
    else if (e < 6291456LL) { seg = 4; base = 5242880LL; }
    else if (e < 6292480LL) { seg = 5; base = 6291456LL; }
    else if (e < 6293504LL) { seg = 6; base = 6292480LL; }
    else if (e < 6294528LL) { seg = 7; base = 6293504LL; }
    else if (e < 6295552LL) { seg = 8; base = 6294528LL; }
    else                    { seg = 9; base = 6295552LL; }
    const long long local = e - base;
    __bf16 tmp[8];
    if (*flag) {
        const float* s = (const float*)srcs.p[seg] + local;
#pragma unroll
        for (int t = 0; t < 8; ++t) tmp[t] = (__bf16)s[t];
        *(bf16x8*)(void*)(dstbase + e) = *(const bf16x8*)tmp;
    } else {
        *(bf16x8*)(void*)(dstbase + e) =
            *(const bf16x8*)(const void*)((const bf16*)srcs.p[seg] + local);
    }
}

// ---------------------------------------------------------------------------
// Fused QKV GEMM, 128x64 tiles (768 blocks -> 3/CU). wsel = blockIdx.x>>4.
// For wsel==2 (V), the epilogue transposes per-head through LDS and writes
// Vt[((b*16+h)*64+d)*SEQ + s] directly (no separate transpose kernel).
// ---------------------------------------------------------------------------
__global__ __launch_bounds__(256) void gemm_qkv_kernel(const bf16* __restrict__ x,
        const bf16* __restrict__ Wq, const bf16* __restrict__ Wk, const bf16* __restrict__ Wv,
        const bf16* __restrict__ bq, const bf16* __restrict__ bk, const bf16* __restrict__ bv,
        bf16* __restrict__ Qb, bf16* __restrict__ Kb, bf16* __restrict__ Vt) {
    const int wsel = blockIdx.x >> 4;
    const int n0 = (blockIdx.x & 15) * 64;
    const int m0 = blockIdx.y * 128;
    const bf16* W    = (wsel == 0) ? Wq : ((wsel == 1) ? Wk : Wv);
    const bf16* bias = (wsel == 0) ? bq : ((wsel == 1) ? bk : bv);

    __shared__ __bf16 As[128][72];
    __shared__ __bf16 Bs[64][72];
    const int tid = threadIdx.x;
    const int wave = tid >> 6, lane = tid & 63, quad = lane >> 4, l16 = lane & 15;
    const int wr = (wave >> 1) * 64, wc = (wave & 1) * 32;
    const int arow = tid >> 1, acg = (tid & 1) * 32;
    const int brow = tid >> 2, bcg = (tid & 3) * 16;

    floatx4 acc[4][2];
#pragma unroll
    for (int r = 0; r < 4; ++r)
#pragma unroll
        for (int c = 0; c < 2; ++c) acc[r][c] = (floatx4)0.f;

    for (int k0 = 0; k0 < 1024; k0 += 64) {
        const bf16* ag = x + (size_t)(m0 + arow) * 1024 + k0 + acg;
        const bf16* bg = W + (size_t)(n0 + brow) * 1024 + k0 + bcg;
        bf16x8 av[4], bv2[2];
#pragma unroll
        for (int c = 0; c < 4; ++c) av[c] = *(const bf16x8*)(const void*)(ag + c * 8);
#pragma unroll
        for (int c = 0; c < 2; ++c) bv2[c] = *(const bf16x8*)(const void*)(bg + c * 8);
        __syncthreads();
#pragma unroll
        for (int c = 0; c < 4; ++c) *(bf16x8*)&As[arow][acg + c * 8] = av[c];
#pragma unroll
        for (int c = 0; c < 2; ++c) *(bf16x8*)&Bs[brow][bcg + c * 8] = bv2[c];
        __syncthreads();
#pragma unroll
        for (int kk = 0; kk < 2; ++kk) {
            bf16x8 af[4], bfr[2];
#pragma unroll
            for (int r = 0; r < 4; ++r)
                af[r] = *(const bf16x8*)&As[wr + r * 16 + l16][kk * 32 + quad * 8];
#pragma unroll
            for (int c = 0; c < 2; ++c)
                bfr[c] = *(const bf16x8*)&Bs[wc + c * 16 + l16][kk * 32 + quad * 8];
#pragma unroll
            for (int r = 0; r < 4; ++r)
#pragma unroll
                for (int c = 0; c < 2; ++c)
                    acc[r][c] = mfma16(af[r], bfr[c], acc[r][c]);
        }
    }

    if (wsel < 2) {
        bf16* Cb = (wsel == 0) ? Qb : Kb;
#pragma unroll
        for (int c = 0; c < 2; ++c) {
            const int col = n0 + wc + c * 16 + l16;
            const float bvl = (float)bias[col];
#pragma unroll
            for (int r = 0; r < 4; ++r)
#pragma unroll
                for (int v = 0; v < 4; ++v) {
                    const int row = m0 + wr + r * 16 + quad * 4 + v;
                    Cb[(size_t)row * 1024 + col] = (bf16)(acc[r][c][v] + bvl);
                }
        }
    } else {
        // transpose epilogue: Ls[d][s_local], stride 132
        __bf16* Ls = &As[0][0];
        __syncthreads();  // all MFMA LDS reads done before overwrite (block-uniform)
#pragma unroll
        for (int c = 0; c < 2; ++c) {
            const int col = wc + c * 16 + l16;  // d
            const float bvl = (float)bias[n0 + col];
#pragma unroll
            for (int r = 0; r < 4; ++r)
#pragma unroll
                for (int v = 0; v < 4; ++v) {
                    const int row = wr + r * 16 + quad * 4 + v;  // s_local
                    Ls[col * 132 + row] = (__bf16)(acc[r][c][v] + bvl);
                }
        }
        __syncthreads();
        const int b = m0 >> 10, s0 = m0 & 1023, h = n0 >> 6;
        const int d = tid >> 2, sg = (tid & 3) * 32;
        bf16* g = Vt + ((size_t)((b * NUM_HEADS + h) * 64 + d)) * SEQ + s0 + sg;
#pragma unroll
        for (int c = 0; c < 32; c += 8)
            *(bf16x8*)(void*)(g + c) = *(const bf16x8*)&Ls[d * 132 + sg + c];
    }
}

// ---------------------------------------------------------------------------
// Flash attention, relative positions. Block = 128 q-rows x (h, b, jsel).
// 256 thr = 4 waves x 32 rows. Grid j-split 2 (each block does 8 j-tiles of 64).
// Unnormalized bf16 O-partials + fp32 (m,l) partials; combine kernel merges.
// Row-sum l is accumulated as a 5th PV output tile against a ones-row in Vs.
//   score(i,j) = ( Q[i].K[j] + Q[i].Er[1023+i-j] ) / 8
//   per-wave BD: T[rl][cl] = Q.Er_window, cl in [0,96); BD[rl][jj]=T[rl][63+rl-jj]
// ---------------------------------------------------------------------------
__global__ __launch_bounds__(256) void attn_mfma_kernel(const bf16* __restrict__ Q,
                                                        const bf16* __restrict__ Kc,
                                                        const bf16* __restrict__ Vt,
                                                        const bf16* __restrict__ Er,
                                                        bf16* __restrict__ Opart,
                                                        float* __restrict__ Ml) {
    const int i0 = blockIdx.x * 128;
    const int h = blockIdx.y;
    const int b = blockIdx.z >> 1, jsel = blockIdx.z & 1;
    const int tid = threadIdx.x;
    const int wave = tid >> 6, lane = tid & 63, quad = lane >> 4, l16 = lane & 15;

    __shared__ __bf16 Ks[64][72];
    __shared__ __bf16 Vs[80][72];        // rows 0..63: V^T tile; row 64: ones; 65..79: 0
    __shared__ __bf16 Ers[192][72];      // Er window rows
    __shared__ __bf16 scr_all[4][3264];  // per-wave: T' [96][34] then P [32][72]
    __bf16* scr = &scr_all[wave][0];
    __bf16* Qs = &scr_all[0][0];         // init-only alias, stride 72, 128 rows

    // ones/zeros rows of Vs (written once; never restaged)
    for (int e = tid; e < 16 * 72; e += 256) {
        const int r = e / 72, c = e - r * 72;
        Vs[64 + r][c] = (r == 0) ? (__bf16)1.0f : (__bf16)0.0f;
    }
    {   // stage Q (128 rows x 64)
        const int r = tid >> 1, cg = (tid & 1) * 32;
        const bf16* g = Q + ((size_t)(b * SEQ + i0 + r)) * D_MODEL + h * 64 + cg;
#pragma unroll
        for (int c = 0; c < 32; c += 8)
            *(bf16x8*)(void*)(Qs + r * 72 + cg + c) = *(const bf16x8*)(const void*)(g + c);
    }
    __syncthreads();
    bf16x8 aq[2][2];
#pragma unroll
    for (int half = 0; half < 2; ++half)
#pragma unroll
        for (int kk = 0; kk < 2; ++kk)
            aq[half][kk] = *(const bf16x8*)(const void*)(
                Qs + (wave * 32 + half * 16 + l16) * 72 + kk * 32 + quad * 8);

    floatx4 oacc[5][2];   // ct 0..3: O columns; ct 4: row-sum l (ones column)
#pragma unroll
    for (int ct = 0; ct < 5; ++ct)
#pragma unroll
        for (int half = 0; half < 2; ++half) oacc[ct][half] = (floatx4)0.f;
    float m_i[2][4];
#pragma unroll
    for (int half = 0; half < 2; ++half)
#pragma unroll
        for (int v = 0; v < 4; ++v) m_i[half][v] = -1e30f;

    const int eb = 960 + i0;  // Er window base (+ row) minus j0
    const bf16* Kg = Kc + (size_t)b * SEQ * D_MODEL + h * 64;
    const bf16* Vtg = Vt + (size_t)((b * NUM_HEADS + h) * 64) * SEQ;

    const int jbeg = jsel * 512, jend = jbeg + 512;
    for (int j0 = jbeg; j0 < jend; j0 += 64) {
        __syncthreads();  // prior-iter Ks/Vs/Ers reads (and init Qs reads) done
        {   // stage K tile, V^T tile, Er window
            const int r4 = tid >> 2, c4 = (tid & 3) * 16;
            const bf16* kg = Kg + (size_t)(j0 + r4) * D_MODEL + c4;
            const bf16* vg = Vtg + (size_t)r4 * SEQ + j0 + c4;
            *(bf16x8*)&Ks[r4][c4]     = *(const bf16x8*)(const void*)kg;
            *(bf16x8*)&Ks[r4][c4 + 8] = *(const bf16x8*)(const void*)(kg + 8);
            *(bf16x8*)&Vs[r4][c4]     = *(const bf16x8*)(const void*)vg;
            *(bf16x8*)&Vs[r4][c4 + 8] = *(const bf16x8*)(const void*)(vg + 8);
            for (int s = tid; s < 384; s += 256) {
                const int er = s >> 1, ecg = (s & 1) * 32;
                const bf16* eg = Er + (size_t)(eb - j0 + er) * 64 + ecg;
#pragma unroll
                for (int c = 0; c < 32; c += 8)
                    *(bf16x8*)&Ers[er][ecg + c] = *(const bf16x8*)(const void*)(eg + c);
            }
        }
        __syncthreads();

        // AC = Q.K^T
        floatx4 sfrag[4][2];
#pragma unroll
        for (int ct = 0; ct < 4; ++ct) {
            bf16x8 bk0 = *(const bf16x8*)&Ks[ct * 16 + l16][quad * 8];
            bf16x8 bk1 = *(const bf16x8*)&Ks[ct * 16 + l16][32 + quad * 8];
#pragma unroll
            for (int half = 0; half < 2; ++half) {
                floatx4 s = (floatx4)0.f;
                s = mfma16(aq[half][0], bk0, s);
                s = mfma16(aq[half][1], bk1, s);
                sfrag[ct][half] = s;
            }
        }
        // BD: compute + immediately spill transposed (wave-private scratch)
#pragma unroll
        for (int ct = 0; ct < 6; ++ct) {
            bf16x8 be0 = *(const bf16x8*)&Ers[wave * 32 + ct * 16 + l16][quad * 8];
            bf16x8 be1 = *(const bf16x8*)&Ers[wave * 32 + ct * 16 + l16][32 + quad * 8];
#pragma unroll
            for (int half = 0; half < 2; ++half) {
                floatx4 t = (floatx4)0.f;
                t = mfma16(aq[half][0], be0, t);
                t = mfma16(aq[half][1], be1, t);
                bf16x4 tv;
#pragma unroll
                for (int v = 0; v < 4; ++v) tv[v] = (__bf16)t[v];
                *(bf16x4*)(void*)(scr + (ct * 16 + l16) * 34 + half * 16 + quad * 4) = tv;
            }
        }
        // gather BD + scale
#pragma unroll
        for (int ct = 0; ct < 4; ++ct)
#pragma unroll
            for (int half = 0; half < 2; ++half)
#pragma unroll
                for (int v = 0; v < 4; ++v) {
                    const int rl = half * 16 + quad * 4 + v;
                    const int cl = 63 + rl - (ct * 16 + l16);
                    sfrag[ct][half][v] =
                        (sfrag[ct][half][v] + (float)scr[cl * 34 + rl]) * 0.125f;
                }
        // online softmax max-update
        float alpha[2][4];
#pragma unroll
        for (int half = 0; half < 2; ++half)
#pragma unroll
            for (int v = 0; v < 4; ++v) {
                float mx = fmaxf(fmaxf(sfrag[0][half][v], sfrag[1][half][v]),
                                 fmaxf(sfrag[2][half][v], sfrag[3][half][v]));
#pragma unroll
                for (int off = 1; off < 16; off <<= 1)
                    mx = fmaxf(mx, __shfl_xor(mx, off, 64));
                const float mnew = fmaxf(m_i[half][v], mx);
                alpha[half][v] = __expf(m_i[half][v] - mnew);
                m_i[half][v] = mnew;
            }
        // P = exp(s - m) -> scratch (T' dead), row-major stride 72
#pragma unroll
        for (int ct = 0; ct < 4; ++ct)
#pragma unroll
            for (int half = 0; half < 2; ++half)
#pragma unroll
                for (int v = 0; v < 4; ++v) {
                    const float p = __expf(sfrag[ct][half][v] - m_i[half][v]);
                    scr[(half * 16 + quad * 4 + v) * 72 + ct * 16 + l16] = (__bf16)p;
                }
        // rescale all accumulators (incl. l column)
#pragma unroll
        for (int ct = 0; ct < 5; ++ct)
#pragma unroll
            for (int half = 0; half < 2; ++half)
#pragma unroll
                for (int v = 0; v < 4; ++v) oacc[ct][half][v] *= alpha[half][v];
        // O += P.V ; l += P.1   (5 b-frag tiles, tile 4 = ones row)
        bf16x8 ap[2][2];
#pragma unroll
        for (int half = 0; half < 2; ++half)
#pragma unroll
            for (int kk = 0; kk < 2; ++kk)
                ap[half][kk] = *(const bf16x8*)(const void*)(
                    scr + (half * 16 + l16) * 72 + kk * 32 + quad * 8);
#pragma unroll
        for (int ct = 0; ct < 5; ++ct) {
            bf16x8 bv0 = *(const bf16x8*)&Vs[ct * 16 + l16][quad * 8];
            bf16x8 bv1 = *(const bf16x8*)&Vs[ct * 16 + l16][32 + quad * 8];
#pragma unroll
            for (int half = 0; half < 2; ++half) {
                oacc[ct][half] = mfma16(ap[half][0], bv0, oacc[ct][half]);
                oacc[ct][half] = mfma16(ap[half][1], bv1, oacc[ct][half]);
            }
        }
    }

    // epilogue: unnormalized bf16 O-partials + (m, l)
    bf16* Op = Opart + (size_t)jsel * 2097152;
#pragma unroll
    for (int ct = 0; ct < 4; ++ct)
#pragma unroll
        for (int half = 0; half < 2; ++half)
#pragma unroll
            for (int v = 0; v < 4; ++v) {
                const int row = i0 + wave * 32 + half * 16 + quad * 4 + v;
                const int col = h * 64 + ct * 16 + l16;
                Op[((size_t)(b * SEQ + row)) * D_MODEL + col] = (bf16)oacc[ct][half][v];
            }
    if (l16 == 0) {
        const int base = ((jsel * 2 + b) * 16 + h) * 1024;
#pragma unroll
        for (int half = 0; half < 2; ++half)
#pragma unroll
            for (int v = 0; v < 4; ++v) {
                const int ig = i0 + wave * 32 + half * 16 + quad * 4 + v;
                Ml[base + ig] = m_i[half][v];
                Ml[65536 + base + ig] = oacc[4][half][v];  // l (ones column, n=0)
            }
    }
}

// ---------------------------------------------------------------------------
// Combine the two j-split partials: O = (e1*O1~ + e2*O2~)/(e1*l1 + e2*l2).
// ---------------------------------------------------------------------------
__global__ __launch_bounds__(256) void combine_kernel(const bf16* __restrict__ Opart,
                                                      const float* __restrict__ Ml,
                                                      bf16* __restrict__ Ob) {
    const int e = (blockIdx.x * 256 + threadIdx.x) * 4;
    const int row = e >> 10, col = e & 1023;
    const int b = row >> 10, i = row & 1023, h = col >> 6;
    const int mb = b * 16384 + h * 1024 + i;
    const float m1 = Ml[mb], m2 = Ml[32768 + mb];
    const float l1 = Ml[65536 + mb], l2 = Ml[65536 + 32768 + mb];
    const float mm = fmaxf(m1, m2);
    const float e1 = __expf(m1 - mm), e2 = __expf(m2 - mm);
    const float inv = 1.0f / (e1 * l1 + e2 * l2);
    bf16x4 o1 = *(const bf16x4*)(const void*)(Opart + e);
    bf16x4 o2 = *(const bf16x4*)(const void*)(Opart + 2097152 + e);
    bf16x4 o;
#pragma unroll
    for (int v = 0; v < 4; ++v)
        o[v] = (__bf16)((e1 * (float)o1[v] + e2 * (float)o2[v]) * inv);
    *(bf16x4*)(void*)(Ob + e) = o;
}

// ---------------------------------------------------------------------------
// Output GEMM: 64x64 tiles (512 blocks -> 2/CU), dual-dtype store.
// ---------------------------------------------------------------------------
__global__ __launch_bounds__(256) void gemm_out_kernel(const bf16* __restrict__ A,
        const bf16* __restrict__ W, const bf16* __restrict__ bias,
        void* __restrict__ C, const int* __restrict__ flag) {
    const int n0 = blockIdx.x * 64;
    const int m0 = blockIdx.y * 64;
    __shared__ __bf16 As[64][72];
    __shared__ __bf16 Bs[64][72];
    const int tid = threadIdx.x;
    const int wave = tid >> 6, lane = tid & 63, quad = lane >> 4, l16 = lane & 15;
    const int wr = (wave >> 1) * 32, wc = (wave & 1) * 32;
    const int srow = tid >> 2, scg = (tid & 3) * 16;

    floatx4 acc[2][2];
#pragma unroll
    for (int r = 0; r < 2; ++r)
#pragma unroll
        for (int c = 0; c < 2; ++c) acc[r][c] = (floatx4)0.f;

    for (int k0 = 0; k0 < 1024; k0 += 64) {
        const bf16* ag = A + (size_t)(m0 + srow) * 1024 + k0 + scg;
        const bf16* bg = W + (size_t)(n0 + srow) * 1024 + k0 + scg;
        bf16x8 av0 = *(const bf16x8*)(const void*)ag;
        bf16x8 av1 = *(const bf16x8*)(const void*)(ag + 8);
        bf16x8 bv0 = *(const bf16x8*)(const void*)bg;
        bf16x8 bv1 = *(const bf16x8*)(const void*)(bg + 8);
        __syncthreads();
        *(bf16x8*)&As[srow][scg]     = av0;
        *(bf16x8*)&As[srow][scg + 8] = av1;
        *(bf16x8*)&Bs[srow][scg]     = bv0;
        *(bf16x8*)&Bs[srow][scg + 8] = bv1;
        __syncthreads();
#pragma unroll
        for (int kk = 0; kk < 2; ++kk) {
            bf16x8 af[2], bfr[2];
#pragma unroll
            for (int r = 0; r < 2; ++r)
                af[r] = *(const bf16x8*)&As[wr + r * 16 + l16][kk * 32 + quad * 8];
#pragma unroll
            for (int c = 0; c < 2; ++c)
                bfr[c] = *(const bf16x8*)&Bs[wc + c * 16 + l16][kk * 32 + quad * 8];
#pragma unroll
            for (int r = 0; r < 2; ++r)
#pragma unroll
                for (int c = 0; c < 2; ++c)
                    acc[r][c] = mfma16(af[r], bfr[c], acc[r][c]);
        }
    }
#pragma unroll
    for (int c = 0; c < 2; ++c) {
        const int col = n0 + wc + c * 16 + l16;
        const float bvl = (float)bias[col];
#pragma unroll
        for (int r = 0; r < 2; ++r)
#pragma unroll
            for (int v = 0; v < 4; ++v) {
                const int row = m0 + wr + r * 16 + quad * 4 + v;
                const float val = acc[r][c][v] + bvl;
                const size_t idx = (size_t)row * 1024 + col;
                if (*flag) ((float*)C)[idx] = val;
                else       ((bf16*)C)[idx] = (bf16)val;
            }
    }
}

// ---------------------------------------------------------------------------
extern "C" void kernel_launch(void* const* d_in, const int* in_sizes, int n_in,
                              void* d_out, int out_size, void* d_ws, size_t ws_size,
                              hipStream_t stream) {
    const size_t E_X = 2097152;       // 2048 x 1024
    const size_t E_CANON = 6426624;

    char* ws = (char*)d_ws;
    int* flag = (int*)ws;
    bf16* canon = (bf16*)(ws + 16);
    bf16* xc  = canon;
    bf16* Wqc = canon + 2097152;
    bf16* Wkc = canon + 3145728;
    bf16* Wvc = canon + 4194304;
    bf16* Woc = canon + 5242880;
    bf16* bqc = canon + 6291456;
    bf16* bkc = canon + 6292480;
    bf16* bvc = canon + 6293504;
    bf16* boc = canon + 6294528;
    bf16* Erc = canon + 6295552;
    bf16* p = canon + E_CANON;
    bf16* Qb    = p;  p += E_X;       // later reused as Ob (combine output)
    bf16* Kb    = p;  p += E_X;
    bf16* Vt    = p;  p += E_X;
    bf16* Opart = p;  p += 2 * E_X;   // bf16 unnormalized partials, 2 splits
    float* Ml   = (float*)p;          // [m|l][2 jsel][2 b][16 h][1024 i] = 131072 f32

    detect_dtype_kernel<<<1, 256, 0, stream>>>(d_in[0], flag);

    ConvSrcs cs;
    cs.p[0] = d_in[0]; cs.p[1] = d_in[1]; cs.p[2] = d_in[3]; cs.p[3] = d_in[5];
    cs.p[4] = d_in[7]; cs.p[5] = d_in[2]; cs.p[6] = d_in[4]; cs.p[7] = d_in[6];
    cs.p[8] = d_in[8]; cs.p[9] = d_in[9];
    convert_all_kernel<<<3138, 256, 0, stream>>>(cs, canon, flag);

    gemm_qkv_kernel<<<dim3(48, 16), 256, 0, stream>>>(xc, Wqc, Wkc, Wvc,
                                                      bqc, bkc, bvc, Qb, Kb, Vt);

    attn_mfma_kernel<<<dim3(8, 16, 4), 256, 0, stream>>>(Qb, Kb, Vt, Erc, Opart, Ml);

    combine_kernel<<<2048, 256, 0, stream>>>(Opart, Ml, Qb);  // Ob overlays Qb

    gemm_out_kernel<<<dim3(16, 32), 256, 0, stream>>>(Qb, Woc, boc, d_out, flag);
}